// Round 9
// baseline (352.430 us; speedup 1.0000x reference)
//
#include <hip/hip_runtime.h>

// Problem constants
#define B_    512
#define D_TRF 5120
#define P_    32
#define E_    160
#define D_OUT 3000
#define PAD_  61
#define D_CL  4998
#define INV_SCALE 0.07905694150420949f   // 1/sqrt(160)
#define N_PAD 3072          // lin_w rows padded (32 tiles of 96)

typedef __attribute__((ext_vector_type(4))) float floatx4;
typedef __attribute__((ext_vector_type(16))) float floatx16;
typedef __attribute__((ext_vector_type(8))) short short8;

static __device__ __forceinline__ unsigned short f2bf(float f) {
    unsigned int u = __float_as_uint(f);
    unsigned int r = (u + 0x7fffu + ((u >> 16) & 1u)) >> 16;
    return (unsigned short)r;
}
static __device__ __forceinline__ float bf2f(unsigned short u) {
    return __uint_as_float(((unsigned int)u) << 16);
}

// ---------------------------------------------------------------------------
// K0: cast lin_w [3000,5120] f32 -> [3072,5120] bf16 (pad rows zeroed)
// ---------------------------------------------------------------------------
__global__ __launch_bounds__(256) void k_castw(const float* __restrict__ w,
                                               unsigned short* __restrict__ wb) {
    size_t i4 = ((size_t)blockIdx.x * 256 + threadIdx.x) * 4;
    size_t o = i4 / D_TRF;
    ushort4 s;
    if (o < D_OUT) {
        float4 v = *(const float4*)(w + i4);
        s.x = f2bf(v.x); s.y = f2bf(v.y); s.z = f2bf(v.z); s.w = f2bf(v.w);
    } else {
        s.x = s.y = s.z = s.w = 0;
    }
    *(ushort4*)(wb + i4) = s;
}

// ---------------------------------------------------------------------------
// K0b: cast wq/wk/wv ([f][e], already B-operand layout) to bf16;
//      transpose bt_w -> wtb[f][e] = bt_w[e][f].
// ---------------------------------------------------------------------------
__global__ __launch_bounds__(256) void k_cast_small(const float* __restrict__ wq,
                                                    const float* __restrict__ wk,
                                                    const float* __restrict__ wv,
                                                    const float* __restrict__ btw,
                                                    unsigned short* __restrict__ wqb,
                                                    unsigned short* __restrict__ wkb,
                                                    unsigned short* __restrict__ wvb,
                                                    unsigned short* __restrict__ wtb) {
    int idx = blockIdx.x * 256 + threadIdx.x;   // < 25600
    wqb[idx] = f2bf(wq[idx]);
    wkb[idx] = f2bf(wk[idx]);
    wvb[idx] = f2bf(wv[idx]);
    int f = idx / E_, e = idx - f * E_;
    wtb[idx] = f2bf(btw[(size_t)e * E_ + f]);
}

// ---------------------------------------------------------------------------
// K1: cl = (x*std+mean) @ mat, with 61-zero pad both sides -> [512,5120]
// ---------------------------------------------------------------------------
__global__ __launch_bounds__(256) void k_cl(const float* __restrict__ x,
                                            const float* __restrict__ stdv,
                                            const float* __restrict__ meanv,
                                            const float* __restrict__ mat,
                                            float* __restrict__ cl) {
    int bg = blockIdx.x, jc = blockIdx.y, tid = threadIdx.x;
    __shared__ float t[8 * 64];
    for (int idx = tid; idx < 8 * 64; idx += 256) {
        int i = idx >> 6, k = idx & 63;
        t[idx] = x[(size_t)(bg * 8 + i) * 64 + k] * stdv[k] + meanv[k];
    }
    __syncthreads();

    if (jc == 0) {
        for (int idx = tid; idx < 8 * PAD_; idx += 256) {
            int i = idx / PAD_, jj = idx - i * PAD_;
            cl[(size_t)(bg * 8 + i) * D_TRF + jj] = 0.f;
        }
    } else if (jc == 3) {
        for (int idx = tid; idx < 8 * PAD_; idx += 256) {
            int i = idx / PAD_, jj = idx - i * PAD_;
            cl[(size_t)(bg * 8 + i) * D_TRF + (D_TRF - PAD_) + jj] = 0.f;
        }
    }

    int j0 = jc * 1250;
    int jend = min(D_CL, j0 + 1250);
    for (int j = j0 + tid; j < jend; j += 256) {
        float acc[8] = {};
        #pragma unroll 16
        for (int k = 0; k < 64; ++k) {
            float m = mat[(size_t)k * D_CL + j];
            #pragma unroll
            for (int i = 0; i < 8; ++i) acc[i] += t[i * 64 + k] * m;
        }
        #pragma unroll
        for (int i = 0; i < 8; ++i)
            cl[(size_t)(bg * 8 + i) * D_TRF + PAD_ + j] = acc[i];
    }
}

// ---------------------------------------------------------------------------
// K2: LayerNorm cl row -> xn bf16 [16384,160]. grid = 512 (one b each)
// ---------------------------------------------------------------------------
__global__ __launch_bounds__(256) void k_ln(const float* __restrict__ cl,
                                            const float* __restrict__ ln_g,
                                            const float* __restrict__ ln_b,
                                            unsigned short* __restrict__ xn) {
    int b = blockIdx.x, tid = threadIdx.x;
    __shared__ float redA[4], redB[4];
    __shared__ float sMu, sRstd;
    const float* row = cl + (size_t)b * D_TRF;

    float s = 0.f, s2 = 0.f;
    #pragma unroll
    for (int it = 0; it < 5; ++it) {
        int i4 = (it * 256 + tid) * 4;
        float4 v = *(const float4*)(row + i4);
        s += v.x + v.y + v.z + v.w;
        s2 += v.x * v.x + v.y * v.y + v.z * v.z + v.w * v.w;
    }
    #pragma unroll
    for (int off = 32; off; off >>= 1) {
        s  += __shfl_down(s, off);
        s2 += __shfl_down(s2, off);
    }
    if ((tid & 63) == 0) { redA[tid >> 6] = s; redB[tid >> 6] = s2; }
    __syncthreads();
    if (tid == 0) {
        float S = redA[0] + redA[1] + redA[2] + redA[3];
        float S2 = redB[0] + redB[1] + redB[2] + redB[3];
        float mu = S / (float)D_TRF;
        float var = S2 / (float)D_TRF - mu * mu;
        sMu = mu; sRstd = rsqrtf(var + 1e-5f);
    }
    __syncthreads();
    float mu = sMu, rs = sRstd;
    #pragma unroll
    for (int it = 0; it < 5; ++it) {
        int i4 = (it * 256 + tid) * 4;
        float4 v = *(const float4*)(row + i4);
        float4 g = *(const float4*)(ln_g + i4);
        float4 be = *(const float4*)(ln_b + i4);
        ushort4 o;
        o.x = f2bf((v.x - mu) * rs * g.x + be.x);
        o.y = f2bf((v.y - mu) * rs * g.y + be.y);
        o.z = f2bf((v.z - mu) * rs * g.z + be.z);
        o.w = f2bf((v.w - mu) * rs * g.w + be.w);
        *(ushort4*)(xn + (size_t)b * D_TRF + i4) = o;
    }
}

// ---------------------------------------------------------------------------
// K3: QKV via MFMA, register-resident B-frags loaded straight from global
// ---------------------------------------------------------------------------
__global__ __launch_bounds__(256) void k_qkv3(const unsigned short* __restrict__ xn,
                                              const unsigned short* __restrict__ wqb,
                                              const unsigned short* __restrict__ wkb,
                                              const unsigned short* __restrict__ wvb,
                                              const float* __restrict__ bq,
                                              const float* __restrict__ bk,
                                              const float* __restrict__ bv,
                                              unsigned short* __restrict__ Qb,
                                              unsigned short* __restrict__ Kb,
                                              unsigned short* __restrict__ Vb) {
    int tid = threadIdx.x, wid = tid >> 6, lane = tid & 63;
    int l16 = lane & 15, quad = lane >> 4;
    int m0 = blockIdx.x * 64 + wid * 16;
    int sel = blockIdx.y;                 // 0..5
    int mat = sel >> 1;
    int cf0 = (sel & 1) * 5;

    const unsigned short* wsrc = (mat == 0) ? wqb : (mat == 1) ? wkb : wvb;
    const float* bias          = (mat == 0) ? bq  : (mat == 1) ? bk  : bv;
    unsigned short* outp       = (mat == 0) ? Qb  : (mat == 1) ? Kb  : Vb;

    short8 a[5];
    const unsigned short* arow = xn + (size_t)(m0 + l16) * E_ + quad * 8;
    #pragma unroll
    for (int kc = 0; kc < 5; ++kc) a[kc] = *(const short8*)(arow + kc * 32);

    #pragma unroll
    for (int c = 0; c < 5; ++c) {
        int cf = cf0 + c;
        floatx4 acc = {0.f, 0.f, 0.f, 0.f};
        const unsigned short* bp = wsrc + (size_t)(cf * 16 + l16) * E_ + quad * 8;
        #pragma unroll
        for (int kc = 0; kc < 5; ++kc) {
            short8 bf = *(const short8*)(bp + kc * 32);
            acc = __builtin_amdgcn_mfma_f32_16x16x32_bf16(a[kc], bf, acc, 0, 0, 0);
        }
        float bb = bias[cf * 16 + l16];
        size_t o = (size_t)(m0 + quad * 4) * E_ + cf * 16 + l16;
        #pragma unroll
        for (int r = 0; r < 4; ++r)
            outp[o + (size_t)r * E_] = f2bf(acc[r] + bb);
    }
}

// ---------------------------------------------------------------------------
// K4: MFMA attention, 4 waves per b (grid 512 x 256). All waves compute
// S = QK^T redundantly; softmax over p in-reg; wave 0 writes att->LDS;
// waves split the 5 PV e-chunks.
// ---------------------------------------------------------------------------
__global__ __launch_bounds__(256) void k_attn3(const unsigned short* __restrict__ Q,
                                               const unsigned short* __restrict__ K,
                                               const unsigned short* __restrict__ V,
                                               const float* __restrict__ cl,
                                               const float* __restrict__ bt_gain,
                                               const float* __restrict__ bt_bias,
                                               float* __restrict__ h,
                                               unsigned short* __restrict__ x2b) {
    int b = blockIdx.x;
    int tid = threadIdx.x, wid = tid >> 6, lane = tid & 63;
    int l32 = lane & 31, hi = lane >> 5;
    __shared__ __align__(16) unsigned short Satt[32 * 40];   // row stride 40 bf16

    const unsigned short* Qg = Q + (size_t)b * D_TRF;
    const unsigned short* Kg = K + (size_t)b * D_TRF;
    const unsigned short* Vg = V + (size_t)b * D_TRF;

    // ---- S = Q K^T (redundant per wave) ----
    floatx16 S = {0.f, 0.f, 0.f, 0.f, 0.f, 0.f, 0.f, 0.f,
                  0.f, 0.f, 0.f, 0.f, 0.f, 0.f, 0.f, 0.f};
    #pragma unroll
    for (int kc = 0; kc < 10; ++kc) {
        int e0 = kc * 16;
        short8 aq = *(const short8*)(Qg + l32 * E_ + e0 + hi * 8);
        short8 bk = *(const short8*)(Kg + l32 * E_ + e0 + hi * 8);
        S = __builtin_amdgcn_mfma_f32_32x32x16_bf16(aq, bk, S, 0, 0, 0);
    }

    // ---- softmax over p (C-layout rows): in-lane 16 regs + shfl_xor(32) ----
    float mx = -1e30f;
    #pragma unroll
    for (int r = 0; r < 16; ++r) { S[r] *= INV_SCALE; mx = fmaxf(mx, S[r]); }
    mx = fmaxf(mx, __shfl_xor(mx, 32));
    float ex[16];
    float sum = 0.f;
    #pragma unroll
    for (int r = 0; r < 16; ++r) { ex[r] = expf(S[r] - mx); sum += ex[r]; }
    sum += __shfl_xor(sum, 32);
    float inv = 1.f / sum;

    // ---- att -> LDS [p][q] bf16 (wave 0 only) ----
    if (wid == 0) {
        #pragma unroll
        for (int r = 0; r < 16; ++r) {
            int p = (r & 3) + 8 * (r >> 2) + 4 * hi;
            Satt[p * 40 + l32] = f2bf(ex[r] * inv);
        }
    }
    __syncthreads();

    // ---- A-frags for PV ----
    short8 a0 = *(const short8*)(&Satt[l32 * 40 + hi * 8]);
    short8 a1 = *(const short8*)(&Satt[l32 * 40 + 16 + hi * 8]);

    const float* clr = cl + (size_t)b * D_TRF;
    float gg = bt_gain[0], bb2 = bt_bias[0];

    for (int t = wid; t < 5; t += 4) {
        int e0 = t * 32;
        short8 b0, b1;
        #pragma unroll
        for (int j = 0; j < 8; ++j) {
            b0[j] = (short)Vg[(size_t)(hi * 8 + j) * E_ + e0 + l32];
            b1[j] = (short)Vg[(size_t)(16 + hi * 8 + j) * E_ + e0 + l32];
        }
        floatx16 acc = {0.f, 0.f, 0.f, 0.f, 0.f, 0.f, 0.f, 0.f,
                        0.f, 0.f, 0.f, 0.f, 0.f, 0.f, 0.f, 0.f};
        acc = __builtin_amdgcn_mfma_f32_32x32x16_bf16(a0, b0, acc, 0, 0, 0);
        acc = __builtin_amdgcn_mfma_f32_32x32x16_bf16(a1, b1, acc, 0, 0, 0);
        #pragma unroll
        for (int r = 0; r < 16; ++r) {
            int p = (r & 3) + 8 * (r >> 2) + 4 * hi;
            int idx = p * E_ + e0 + l32;
            float hv = acc[r] + clr[idx];
            h[(size_t)b * D_TRF + idx] = hv;
            x2b[(size_t)b * D_TRF + idx] = f2bf(hv * gg + bb2);
        }
    }
}

// ---------------------------------------------------------------------------
// K5: Better_Transformer via MFMA, register B-frags from global (no LDS).
// ---------------------------------------------------------------------------
__global__ __launch_bounds__(256) void k_bt3(const unsigned short* __restrict__ x2b,
                                             const unsigned short* __restrict__ wtb,
                                             const float* __restrict__ bt_b,
                                             const float* __restrict__ sup_g,
                                             const float* __restrict__ sup_b,
                                             const float* __restrict__ h,
                                             unsigned short* __restrict__ yb) {
    int tid = threadIdx.x, wid = tid >> 6, lane = tid & 63;
    int l16 = lane & 15, quad = lane >> 4;
    int m0 = blockIdx.x * 64 + wid * 16;
    int cf0 = blockIdx.y * 5;

    short8 a[5];
    const unsigned short* arow = x2b + (size_t)(m0 + l16) * E_ + quad * 8;
    #pragma unroll
    for (int kc = 0; kc < 5; ++kc) a[kc] = *(const short8*)(arow + kc * 32);

    #pragma unroll
    for (int c = 0; c < 5; ++c) {
        int cf = cf0 + c;
        floatx4 acc = {0.f, 0.f, 0.f, 0.f};
        const unsigned short* bp = wtb + (size_t)(cf * 16 + l16) * E_ + quad * 8;
        #pragma unroll
        for (int kc = 0; kc < 5; ++kc) {
            short8 bf = *(const short8*)(bp + kc * 32);
            acc = __builtin_amdgcn_mfma_f32_16x16x32_bf16(a[kc], bf, acc, 0, 0, 0);
        }
        int col = cf * 16 + l16;
        float bb = bt_b[col];
        #pragma unroll
        for (int r = 0; r < 4; ++r) {
            int row = m0 + quad * 4 + r;
            int p = row & 31;
            int i = p * E_ + col;
            float o = acc[r] + bb;
            float sig = 1.f / (1.f + expf(-sup_b[i] * o));
            float y = (sup_g[i] + sig * (1.f - sup_g[i])) * o + h[(size_t)row * E_ + col];
            yb[(size_t)row * E_ + col] = f2bf(y);
        }
    }
}

// ---------------------------------------------------------------------------
// K6: init out with bias terms: out[row,col] = lin_b[col]*g + ob
// ---------------------------------------------------------------------------
__global__ __launch_bounds__(256) void k_init_out(const float* __restrict__ lin_b,
                                                  const float* __restrict__ out_gain,
                                                  const float* __restrict__ out_bias,
                                                  float* __restrict__ out) {
    int col = blockIdx.x * 256 + threadIdx.x;
    if (col >= D_OUT) return;
    out[(size_t)blockIdx.y * D_OUT + col] = lin_b[col] * out_gain[0] + out_bias[0];
}

// ---------------------------------------------------------------------------
// K7: head GEMM v5 — NO LDS, NO barrier (k_qkv3 structure scaled up).
// Register ping-pong: load frags for k+32 from global while MFMA'ing k.
// Tile 128(m) x 96(n) per block, 4 waves 2x2 (wave 64x48, 4x3 frags),
// split-K 8 -> grid 1024 = 4 blocks/CU (~4 waves/SIMD to hide L2 latency).
// A (5 MB) and B (31 MB) are L2/L3-resident; fine-grained vmcnt per use,
// no vmcnt(0) drain anywhere in the loop. atomicAdd epilogue.
// ---------------------------------------------------------------------------
__global__ __launch_bounds__(256) void k_lin5(const unsigned short* __restrict__ yb,
                                              const unsigned short* __restrict__ wb,
                                              const float* __restrict__ out_gain,
                                              float* __restrict__ out) {
    int blk = blockIdx.x;
    int n = blk & 31, mt = (blk >> 5) & 3, sp = blk >> 7;   // sp 0..7
    int tid = threadIdx.x, wid = tid >> 6, lane = tid & 63;
    int wm = wid >> 1, wn = wid & 1;
    int l16 = lane & 15, quad = lane >> 4;
    int m_base = mt * 128;

    const unsigned short* Ar[4];
    const unsigned short* Br[3];
    #pragma unroll
    for (int fi = 0; fi < 4; ++fi)
        Ar[fi] = yb + (size_t)(m_base + wm * 64 + fi * 16 + l16) * D_TRF + quad * 8;
    #pragma unroll
    for (int fj = 0; fj < 3; ++fj)
        Br[fj] = wb + (size_t)(n * 96 + wn * 48 + fj * 16 + l16) * D_TRF + quad * 8;

    floatx4 acc[4][3];
    #pragma unroll
    for (int i = 0; i < 4; ++i)
        #pragma unroll
        for (int j = 0; j < 3; ++j) acc[i][j] = (floatx4){0.f, 0.f, 0.f, 0.f};

    const int k0 = sp * (D_TRF / 8);         // 640 per split, 20 k-steps
    short8 aP[4], bP[3], aN[4], bN[3];

    #pragma unroll
    for (int fi = 0; fi < 4; ++fi) aP[fi] = *(const short8*)(Ar[fi] + k0);
    #pragma unroll
    for (int fj = 0; fj < 3; ++fj) bP[fj] = *(const short8*)(Br[fj] + k0);

    for (int it = 0; it < 10; ++it) {
        int kN = k0 + it * 64 + 32;
        #pragma unroll
        for (int fi = 0; fi < 4; ++fi) aN[fi] = *(const short8*)(Ar[fi] + kN);
        #pragma unroll
        for (int fj = 0; fj < 3; ++fj) bN[fj] = *(const short8*)(Br[fj] + kN);
        #pragma unroll
        for (int fi = 0; fi < 4; ++fi)
            #pragma unroll
            for (int fj = 0; fj < 3; ++fj)
                acc[fi][fj] = __builtin_amdgcn_mfma_f32_16x16x32_bf16(aP[fi], bP[fj], acc[fi][fj], 0, 0, 0);

        int kP = (it < 9) ? (k0 + it * 64 + 64) : k0;   // wrap: values unused
        #pragma unroll
        for (int fi = 0; fi < 4; ++fi) aP[fi] = *(const short8*)(Ar[fi] + kP);
        #pragma unroll
        for (int fj = 0; fj < 3; ++fj) bP[fj] = *(const short8*)(Br[fj] + kP);
        #pragma unroll
        for (int fi = 0; fi < 4; ++fi)
            #pragma unroll
            for (int fj = 0; fj < 3; ++fj)
                acc[fi][fj] = __builtin_amdgcn_mfma_f32_16x16x32_bf16(aN[fi], bN[fj], acc[fi][fj], 0, 0, 0);
    }

    float g = out_gain[0];
    #pragma unroll
    for (int fi = 0; fi < 4; ++fi) {
        int row = m_base + wm * 64 + fi * 16 + quad * 4;
        #pragma unroll
        for (int fj = 0; fj < 3; ++fj) {
            int col = n * 96 + wn * 48 + fj * 16 + l16;
            if (col >= D_OUT) continue;
            #pragma unroll
            for (int r = 0; r < 4; ++r)
                atomicAdd(&out[(size_t)(row + r) * D_OUT + col], acc[fi][fj][r] * g);
        }
    }
}

// ---------------------------------------------------------------------------
// Workspace layout (bytes)
// ---------------------------------------------------------------------------
#define SZ_ROWF ((size_t)B_ * D_TRF * 4)           // 10,485,760
#define SZ_ROWB ((size_t)B_ * D_TRF * 2)           // 5,242,880
#define OFF_CL  ((size_t)0)
#define OFF_H   (OFF_CL + SZ_ROWF)
#define OFF_XN  (OFF_H + SZ_ROWF)                  // xn bf16; reused as x2b
#define OFF_QB  (OFF_XN + SZ_ROWB)
#define OFF_KB  (OFF_QB + SZ_ROWB)
#define OFF_VB  (OFF_KB + SZ_ROWB)
#define OFF_YB  (OFF_VB + SZ_ROWB)
#define OFF_WSM (OFF_YB + SZ_ROWB)                 // 4 x 51200 B
#define OFF_WB  (OFF_WSM + (size_t)4 * E_ * E_ * 2)
// end = OFF_WB + 3072*5120*2 = 78,848,000 bytes

extern "C" void kernel_launch(void* const* d_in, const int* in_sizes, int n_in,
                              void* d_out, int out_size, void* d_ws, size_t ws_size,
                              hipStream_t stream) {
    const float* x        = (const float*)d_in[0];
    const float* stdv     = (const float*)d_in[1];
    const float* meanv    = (const float*)d_in[2];
    const float* mat      = (const float*)d_in[3];
    const float* ln_g     = (const float*)d_in[4];
    const float* ln_b     = (const float*)d_in[5];
    const float* wq       = (const float*)d_in[6];
    const float* bq       = (const float*)d_in[7];
    const float* wk       = (const float*)d_in[8];
    const float* bk       = (const float*)d_in[9];
    const float* wv       = (const float*)d_in[10];
    const float* bv       = (const float*)d_in[11];
    const float* bt_w     = (const float*)d_in[12];
    const float* bt_b     = (const float*)d_in[13];
    const float* bt_gain  = (const float*)d_in[14];
    const float* bt_bias  = (const float*)d_in[15];
    const float* sup_g    = (const float*)d_in[16];
    const float* sup_b    = (const float*)d_in[17];
    const float* lin_w    = (const float*)d_in[18];
    const float* lin_b    = (const float*)d_in[19];
    const float* out_gain = (const float*)d_in[20];
    const float* out_bias = (const float*)d_in[21];

    char* ws = (char*)d_ws;
    float* cl = (float*)(ws + OFF_CL);
    float* h  = (float*)(ws + OFF_H);
    unsigned short* xn  = (unsigned short*)(ws + OFF_XN);
    unsigned short* x2b = xn;   // xn dead after k_qkv3
    unsigned short* Qb  = (unsigned short*)(ws + OFF_QB);
    unsigned short* Kb  = (unsigned short*)(ws + OFF_KB);
    unsigned short* Vb  = (unsigned short*)(ws + OFF_VB);
    unsigned short* yb  = (unsigned short*)(ws + OFF_YB);
    unsigned short* wqb = (unsigned short*)(ws + OFF_WSM);
    unsigned short* wkb = wqb + E_ * E_;
    unsigned short* wvb = wkb + E_ * E_;
    unsigned short* wtb = wvb + E_ * E_;
    unsigned short* wb  = (unsigned short*)(ws + OFF_WB);
    float* out = (float*)d_out;

    k_castw<<<15360, 256, 0, stream>>>(lin_w, wb);
    k_cast_small<<<100, 256, 0, stream>>>(wq, wk, wv, bt_w, wqb, wkb, wvb, wtb);
    k_cl<<<dim3(64, 4), 256, 0, stream>>>(x, stdv, meanv, mat, cl);
    k_ln<<<512, 256, 0, stream>>>(cl, ln_g, ln_b, xn);
    k_qkv3<<<dim3(256, 6), 256, 0, stream>>>(xn, wqb, wkb, wvb, bq, bk, bv, Qb, Kb, Vb);
    k_attn3<<<512, 256, 0, stream>>>(Qb, Kb, Vb, cl, bt_gain, bt_bias, h, x2b);
    k_bt3<<<dim3(256, 2), 256, 0, stream>>>(x2b, wtb, bt_b, sup_g, sup_b, h, yb);
    k_init_out<<<dim3(12, B_), 256, 0, stream>>>(lin_b, out_gain, out_bias, out);
    k_lin5<<<1024, 256, 0, stream>>>(yb, wb, out_gain, out);
}

// Round 10
// 295.224 us; speedup vs baseline: 1.1938x; 1.1938x over previous
//
#include <hip/hip_runtime.h>

// Problem constants
#define B_    512
#define D_TRF 5120
#define P_    32
#define E_    160
#define D_OUT 3000
#define PAD_  61
#define D_CL  4998
#define INV_SCALE 0.07905694150420949f   // 1/sqrt(160)
#define N_PAD 3072          // lin_w rows padded (64 tiles of 48)

typedef __attribute__((ext_vector_type(4))) float floatx4;
typedef __attribute__((ext_vector_type(16))) float floatx16;
typedef __attribute__((ext_vector_type(8))) short short8;

static __device__ __forceinline__ unsigned short f2bf(float f) {
    unsigned int u = __float_as_uint(f);
    unsigned int r = (u + 0x7fffu + ((u >> 16) & 1u)) >> 16;
    return (unsigned short)r;
}
static __device__ __forceinline__ float bf2f(unsigned short u) {
    return __uint_as_float(((unsigned int)u) << 16);
}
static __device__ __forceinline__ void load_lds16(const void* g, void* lds) {
    __builtin_amdgcn_global_load_lds(
        (const __attribute__((address_space(1))) unsigned int*)g,
        (__attribute__((address_space(3))) unsigned int*)lds, 16, 0, 0);
}

// ---------------------------------------------------------------------------
// K0: cast lin_w [3000,5120] f32 -> [3072,5120] bf16 (pad rows zeroed)
// ---------------------------------------------------------------------------
__global__ __launch_bounds__(256) void k_castw(const float* __restrict__ w,
                                               unsigned short* __restrict__ wb) {
    size_t i4 = ((size_t)blockIdx.x * 256 + threadIdx.x) * 4;
    size_t o = i4 / D_TRF;
    ushort4 s;
    if (o < D_OUT) {
        float4 v = *(const float4*)(w + i4);
        s.x = f2bf(v.x); s.y = f2bf(v.y); s.z = f2bf(v.z); s.w = f2bf(v.w);
    } else {
        s.x = s.y = s.z = s.w = 0;
    }
    *(ushort4*)(wb + i4) = s;
}

// ---------------------------------------------------------------------------
// K0b: cast wq/wk/wv ([f][e], already B-operand layout) to bf16;
//      transpose bt_w -> wtb[f][e] = bt_w[e][f].
// ---------------------------------------------------------------------------
__global__ __launch_bounds__(256) void k_cast_small(const float* __restrict__ wq,
                                                    const float* __restrict__ wk,
                                                    const float* __restrict__ wv,
                                                    const float* __restrict__ btw,
                                                    unsigned short* __restrict__ wqb,
                                                    unsigned short* __restrict__ wkb,
                                                    unsigned short* __restrict__ wvb,
                                                    unsigned short* __restrict__ wtb) {
    int idx = blockIdx.x * 256 + threadIdx.x;   // < 25600
    wqb[idx] = f2bf(wq[idx]);
    wkb[idx] = f2bf(wk[idx]);
    wvb[idx] = f2bf(wv[idx]);
    int f = idx / E_, e = idx - f * E_;
    wtb[idx] = f2bf(btw[(size_t)e * E_ + f]);
}

// ---------------------------------------------------------------------------
// K1: cl = (x*std+mean) @ mat, with 61-zero pad both sides -> [512,5120]
// ---------------------------------------------------------------------------
__global__ __launch_bounds__(256) void k_cl(const float* __restrict__ x,
                                            const float* __restrict__ stdv,
                                            const float* __restrict__ meanv,
                                            const float* __restrict__ mat,
                                            float* __restrict__ cl) {
    int bg = blockIdx.x, jc = blockIdx.y, tid = threadIdx.x;
    __shared__ float t[8 * 64];
    for (int idx = tid; idx < 8 * 64; idx += 256) {
        int i = idx >> 6, k = idx & 63;
        t[idx] = x[(size_t)(bg * 8 + i) * 64 + k] * stdv[k] + meanv[k];
    }
    __syncthreads();

    if (jc == 0) {
        for (int idx = tid; idx < 8 * PAD_; idx += 256) {
            int i = idx / PAD_, jj = idx - i * PAD_;
            cl[(size_t)(bg * 8 + i) * D_TRF + jj] = 0.f;
        }
    } else if (jc == 3) {
        for (int idx = tid; idx < 8 * PAD_; idx += 256) {
            int i = idx / PAD_, jj = idx - i * PAD_;
            cl[(size_t)(bg * 8 + i) * D_TRF + (D_TRF - PAD_) + jj] = 0.f;
        }
    }

    int j0 = jc * 1250;
    int jend = min(D_CL, j0 + 1250);
    for (int j = j0 + tid; j < jend; j += 256) {
        float acc[8] = {};
        #pragma unroll 16
        for (int k = 0; k < 64; ++k) {
            float m = mat[(size_t)k * D_CL + j];
            #pragma unroll
            for (int i = 0; i < 8; ++i) acc[i] += t[i * 64 + k] * m;
        }
        #pragma unroll
        for (int i = 0; i < 8; ++i)
            cl[(size_t)(bg * 8 + i) * D_TRF + PAD_ + j] = acc[i];
    }
}

// ---------------------------------------------------------------------------
// K2: LayerNorm cl row -> xn bf16 [16384,160]. grid = 512 (one b each)
// ---------------------------------------------------------------------------
__global__ __launch_bounds__(256) void k_ln(const float* __restrict__ cl,
                                            const float* __restrict__ ln_g,
                                            const float* __restrict__ ln_b,
                                            unsigned short* __restrict__ xn) {
    int b = blockIdx.x, tid = threadIdx.x;
    __shared__ float redA[4], redB[4];
    __shared__ float sMu, sRstd;
    const float* row = cl + (size_t)b * D_TRF;

    float s = 0.f, s2 = 0.f;
    #pragma unroll
    for (int it = 0; it < 5; ++it) {
        int i4 = (it * 256 + tid) * 4;
        float4 v = *(const float4*)(row + i4);
        s += v.x + v.y + v.z + v.w;
        s2 += v.x * v.x + v.y * v.y + v.z * v.z + v.w * v.w;
    }
    #pragma unroll
    for (int off = 32; off; off >>= 1) {
        s  += __shfl_down(s, off);
        s2 += __shfl_down(s2, off);
    }
    if ((tid & 63) == 0) { redA[tid >> 6] = s; redB[tid >> 6] = s2; }
    __syncthreads();
    if (tid == 0) {
        float S = redA[0] + redA[1] + redA[2] + redA[3];
        float S2 = redB[0] + redB[1] + redB[2] + redB[3];
        float mu = S / (float)D_TRF;
        float var = S2 / (float)D_TRF - mu * mu;
        sMu = mu; sRstd = rsqrtf(var + 1e-5f);
    }
    __syncthreads();
    float mu = sMu, rs = sRstd;
    #pragma unroll
    for (int it = 0; it < 5; ++it) {
        int i4 = (it * 256 + tid) * 4;
        float4 v = *(const float4*)(row + i4);
        float4 g = *(const float4*)(ln_g + i4);
        float4 be = *(const float4*)(ln_b + i4);
        ushort4 o;
        o.x = f2bf((v.x - mu) * rs * g.x + be.x);
        o.y = f2bf((v.y - mu) * rs * g.y + be.y);
        o.z = f2bf((v.z - mu) * rs * g.z + be.z);
        o.w = f2bf((v.w - mu) * rs * g.w + be.w);
        *(ushort4*)(xn + (size_t)b * D_TRF + i4) = o;
    }
}

// ---------------------------------------------------------------------------
// K3: QKV via MFMA, register-resident B-frags loaded straight from global
// ---------------------------------------------------------------------------
__global__ __launch_bounds__(256) void k_qkv3(const unsigned short* __restrict__ xn,
                                              const unsigned short* __restrict__ wqb,
                                              const unsigned short* __restrict__ wkb,
                                              const unsigned short* __restrict__ wvb,
                                              const float* __restrict__ bq,
                                              const float* __restrict__ bk,
                                              const float* __restrict__ bv,
                                              unsigned short* __restrict__ Qb,
                                              unsigned short* __restrict__ Kb,
                                              unsigned short* __restrict__ Vb) {
    int tid = threadIdx.x, wid = tid >> 6, lane = tid & 63;
    int l16 = lane & 15, quad = lane >> 4;
    int m0 = blockIdx.x * 64 + wid * 16;
    int sel = blockIdx.y;                 // 0..5
    int mat = sel >> 1;
    int cf0 = (sel & 1) * 5;

    const unsigned short* wsrc = (mat == 0) ? wqb : (mat == 1) ? wkb : wvb;
    const float* bias          = (mat == 0) ? bq  : (mat == 1) ? bk  : bv;
    unsigned short* outp       = (mat == 0) ? Qb  : (mat == 1) ? Kb  : Vb;

    short8 a[5];
    const unsigned short* arow = xn + (size_t)(m0 + l16) * E_ + quad * 8;
    #pragma unroll
    for (int kc = 0; kc < 5; ++kc) a[kc] = *(const short8*)(arow + kc * 32);

    #pragma unroll
    for (int c = 0; c < 5; ++c) {
        int cf = cf0 + c;
        floatx4 acc = {0.f, 0.f, 0.f, 0.f};
        const unsigned short* bp = wsrc + (size_t)(cf * 16 + l16) * E_ + quad * 8;
        #pragma unroll
        for (int kc = 0; kc < 5; ++kc) {
            short8 bf = *(const short8*)(bp + kc * 32);
            acc = __builtin_amdgcn_mfma_f32_16x16x32_bf16(a[kc], bf, acc, 0, 0, 0);
        }
        float bb = bias[cf * 16 + l16];
        size_t o = (size_t)(m0 + quad * 4) * E_ + cf * 16 + l16;
        #pragma unroll
        for (int r = 0; r < 4; ++r)
            outp[o + (size_t)r * E_] = f2bf(acc[r] + bb);
    }
}

// ---------------------------------------------------------------------------
// K4: MFMA attention, 4 waves per b (grid 512 x 256). All waves compute
// S = QK^T redundantly; softmax over p in-reg; wave 0 writes att->LDS;
// waves split the 5 PV e-chunks.
// ---------------------------------------------------------------------------
__global__ __launch_bounds__(256) void k_attn3(const unsigned short* __restrict__ Q,
                                               const unsigned short* __restrict__ K,
                                               const unsigned short* __restrict__ V,
                                               const float* __restrict__ cl,
                                               const float* __restrict__ bt_gain,
                                               const float* __restrict__ bt_bias,
                                               float* __restrict__ h,
                                               unsigned short* __restrict__ x2b) {
    int b = blockIdx.x;
    int tid = threadIdx.x, wid = tid >> 6, lane = tid & 63;
    int l32 = lane & 31, hi = lane >> 5;
    __shared__ __align__(16) unsigned short Satt[32 * 40];   // row stride 40 bf16

    const unsigned short* Qg = Q + (size_t)b * D_TRF;
    const unsigned short* Kg = K + (size_t)b * D_TRF;
    const unsigned short* Vg = V + (size_t)b * D_TRF;

    // ---- S = Q K^T (redundant per wave) ----
    floatx16 S = {0.f, 0.f, 0.f, 0.f, 0.f, 0.f, 0.f, 0.f,
                  0.f, 0.f, 0.f, 0.f, 0.f, 0.f, 0.f, 0.f};
    #pragma unroll
    for (int kc = 0; kc < 10; ++kc) {
        int e0 = kc * 16;
        short8 aq = *(const short8*)(Qg + l32 * E_ + e0 + hi * 8);
        short8 bk = *(const short8*)(Kg + l32 * E_ + e0 + hi * 8);
        S = __builtin_amdgcn_mfma_f32_32x32x16_bf16(aq, bk, S, 0, 0, 0);
    }

    // ---- softmax over p (C-layout rows): in-lane 16 regs + shfl_xor(32) ----
    float mx = -1e30f;
    #pragma unroll
    for (int r = 0; r < 16; ++r) { S[r] *= INV_SCALE; mx = fmaxf(mx, S[r]); }
    mx = fmaxf(mx, __shfl_xor(mx, 32));
    float ex[16];
    float sum = 0.f;
    #pragma unroll
    for (int r = 0; r < 16; ++r) { ex[r] = expf(S[r] - mx); sum += ex[r]; }
    sum += __shfl_xor(sum, 32);
    float inv = 1.f / sum;

    // ---- att -> LDS [p][q] bf16 (wave 0 only) ----
    if (wid == 0) {
        #pragma unroll
        for (int r = 0; r < 16; ++r) {
            int p = (r & 3) + 8 * (r >> 2) + 4 * hi;
            Satt[p * 40 + l32] = f2bf(ex[r] * inv);
        }
    }
    __syncthreads();

    // ---- A-frags for PV ----
    short8 a0 = *(const short8*)(&Satt[l32 * 40 + hi * 8]);
    short8 a1 = *(const short8*)(&Satt[l32 * 40 + 16 + hi * 8]);

    const float* clr = cl + (size_t)b * D_TRF;
    float gg = bt_gain[0], bb2 = bt_bias[0];

    for (int t = wid; t < 5; t += 4) {
        int e0 = t * 32;
        short8 b0, b1;
        #pragma unroll
        for (int j = 0; j < 8; ++j) {
            b0[j] = (short)Vg[(size_t)(hi * 8 + j) * E_ + e0 + l32];
            b1[j] = (short)Vg[(size_t)(16 + hi * 8 + j) * E_ + e0 + l32];
        }
        floatx16 acc = {0.f, 0.f, 0.f, 0.f, 0.f, 0.f, 0.f, 0.f,
                        0.f, 0.f, 0.f, 0.f, 0.f, 0.f, 0.f, 0.f};
        acc = __builtin_amdgcn_mfma_f32_32x32x16_bf16(a0, b0, acc, 0, 0, 0);
        acc = __builtin_amdgcn_mfma_f32_32x32x16_bf16(a1, b1, acc, 0, 0, 0);
        #pragma unroll
        for (int r = 0; r < 16; ++r) {
            int p = (r & 3) + 8 * (r >> 2) + 4 * hi;
            int idx = p * E_ + e0 + l32;
            float hv = acc[r] + clr[idx];
            h[(size_t)b * D_TRF + idx] = hv;
            x2b[(size_t)b * D_TRF + idx] = f2bf(hv * gg + bb2);
        }
    }
}

// ---------------------------------------------------------------------------
// K5: Better_Transformer via MFMA, register B-frags from global (no LDS).
// ---------------------------------------------------------------------------
__global__ __launch_bounds__(256) void k_bt3(const unsigned short* __restrict__ x2b,
                                             const unsigned short* __restrict__ wtb,
                                             const float* __restrict__ bt_b,
                                             const float* __restrict__ sup_g,
                                             const float* __restrict__ sup_b,
                                             const float* __restrict__ h,
                                             unsigned short* __restrict__ yb) {
    int tid = threadIdx.x, wid = tid >> 6, lane = tid & 63;
    int l16 = lane & 15, quad = lane >> 4;
    int m0 = blockIdx.x * 64 + wid * 16;
    int cf0 = blockIdx.y * 5;

    short8 a[5];
    const unsigned short* arow = x2b + (size_t)(m0 + l16) * E_ + quad * 8;
    #pragma unroll
    for (int kc = 0; kc < 5; ++kc) a[kc] = *(const short8*)(arow + kc * 32);

    #pragma unroll
    for (int c = 0; c < 5; ++c) {
        int cf = cf0 + c;
        floatx4 acc = {0.f, 0.f, 0.f, 0.f};
        const unsigned short* bp = wtb + (size_t)(cf * 16 + l16) * E_ + quad * 8;
        #pragma unroll
        for (int kc = 0; kc < 5; ++kc) {
            short8 bf = *(const short8*)(bp + kc * 32);
            acc = __builtin_amdgcn_mfma_f32_16x16x32_bf16(a[kc], bf, acc, 0, 0, 0);
        }
        int col = cf * 16 + l16;
        float bb = bt_b[col];
        #pragma unroll
        for (int r = 0; r < 4; ++r) {
            int row = m0 + quad * 4 + r;
            int p = row & 31;
            int i = p * E_ + col;
            float o = acc[r] + bb;
            float sig = 1.f / (1.f + expf(-sup_b[i] * o));
            float y = (sup_g[i] + sig * (1.f - sup_g[i])) * o + h[(size_t)row * E_ + col];
            yb[(size_t)row * E_ + col] = f2bf(y);
        }
    }
}

// ---------------------------------------------------------------------------
// K7: head GEMM v6 — one-shot bulk LDS staging of B, no per-iter barrier,
// no atomics. grid 256 = 64 n-tiles(48) x 4 k-splits(1280).
// Per block: Bs = 48 x 640 bf16 (60 KB), staged twice (two 640-k halves)
// via global_load_lds with XOR chunk swizzle applied on the GLOBAL side
// (slot u holds global chunk (u%80)^((u/80)&7)) so LDS dests stay
// wave-contiguous while ds_reads land 2-way conflict-free.
// 4 waves x 64 m x 2 m-chunks = 512 m; wave frags 4x3; A direct from L2
// (k_qkv3-proven pattern), register ping-pong on A and B.
// Partials -> pb[sp][512][3072] f32, reduced by k_red. B HBM cost is paid
// ONCE at bandwidth (all blocks' bulk stages in flight together), not
// per-iteration at latency — that was k_lin2/4/5's shared disease.
// ---------------------------------------------------------------------------
__global__ __launch_bounds__(256) void k_lin6(const unsigned short* __restrict__ yb,
                                              const unsigned short* __restrict__ wb,
                                              float* __restrict__ pb) {
    __shared__ __align__(16) unsigned short Bs[48 * 640];   // 60 KB
    int blk = blockIdx.x;
    int nt = blk & 63, sp = blk >> 6;        // 64 n-tiles, 4 k-splits
    int tid = threadIdx.x, wid = tid >> 6, lane = tid & 63;
    int l16 = lane & 15, quad = lane >> 4;
    int br7 = l16 & 7;

    floatx4 acc[2][4][3];
    #pragma unroll
    for (int mc = 0; mc < 2; ++mc)
        #pragma unroll
        for (int i = 0; i < 4; ++i)
            #pragma unroll
            for (int j = 0; j < 3; ++j) acc[mc][i][j] = (floatx4){0.f, 0.f, 0.f, 0.f};

    int bbase[3];
    #pragma unroll
    for (int fj = 0; fj < 3; ++fj) bbase[fj] = (fj * 16 + l16) * 640;

    const int k0 = sp * 1280;
    for (int h = 0; h < 2; ++h) {
        int kh = k0 + h * 640;
        if (h) __syncthreads();              // all waves done reading half 0
        #pragma unroll
        for (int i = 0; i < 15; ++i) {       // 3840 slots of 16 B
            int u = i * 256 + tid;
            int row = u / 80;                // 80 chunks per row
            int c = u - row * 80;
            int g = c ^ (row & 7);           // XOR swizzle on global side
            load_lds16(wb + (size_t)(nt * 48 + row) * D_TRF + kh + g * 8,
                       (char*)Bs + (size_t)u * 16);
        }
        __syncthreads();

        for (int mc = 0; mc < 2; ++mc) {
            const unsigned short* Ar[4];
            #pragma unroll
            for (int fi = 0; fi < 4; ++fi)
                Ar[fi] = yb + (size_t)(mc * 256 + wid * 64 + fi * 16 + l16) * D_TRF
                         + quad * 8 + kh;

            short8 aP[4], bP[3], aN[4], bN[3];
            #pragma unroll
            for (int fi = 0; fi < 4; ++fi) aP[fi] = *(const short8*)(Ar[fi]);
            #pragma unroll
            for (int fj = 0; fj < 3; ++fj)
                bP[fj] = *(const short8*)(Bs + bbase[fj] + ((quad ^ br7) * 8));

            for (int it = 0; it < 10; ++it) {
                int s1 = 2 * it + 1;
                #pragma unroll
                for (int fi = 0; fi < 4; ++fi)
                    aN[fi] = *(const short8*)(Ar[fi] + s1 * 32);
                #pragma unroll
                for (int fj = 0; fj < 3; ++fj) {
                    int c = s1 * 4 + quad;
                    bN[fj] = *(const short8*)(Bs + bbase[fj] + ((c ^ br7) * 8));
                }
                #pragma unroll
                for (int fi = 0; fi < 4; ++fi)
                    #pragma unroll
                    for (int fj = 0; fj < 3; ++fj)
                        acc[mc][fi][fj] = __builtin_amdgcn_mfma_f32_16x16x32_bf16(
                            aP[fi], bP[fj], acc[mc][fi][fj], 0, 0, 0);

                int s2 = (it < 9) ? 2 * it + 2 : 0;   // wrap: dummy, unused
                #pragma unroll
                for (int fi = 0; fi < 4; ++fi)
                    aP[fi] = *(const short8*)(Ar[fi] + s2 * 32);
                #pragma unroll
                for (int fj = 0; fj < 3; ++fj) {
                    int c = s2 * 4 + quad;
                    bP[fj] = *(const short8*)(Bs + bbase[fj] + ((c ^ br7) * 8));
                }
                #pragma unroll
                for (int fi = 0; fi < 4; ++fi)
                    #pragma unroll
                    for (int fj = 0; fj < 3; ++fj)
                        acc[mc][fi][fj] = __builtin_amdgcn_mfma_f32_16x16x32_bf16(
                            aN[fi], bN[fj], acc[mc][fi][fj], 0, 0, 0);
            }
        }
    }

    // epilogue: plain coalesced stores of partials
    #pragma unroll
    for (int mc = 0; mc < 2; ++mc)
        #pragma unroll
        for (int fi = 0; fi < 4; ++fi) {
            int row = mc * 256 + wid * 64 + fi * 16 + quad * 4;
            #pragma unroll
            for (int fj = 0; fj < 3; ++fj) {
                int col = nt * 48 + fj * 16 + l16;
                #pragma unroll
                for (int r = 0; r < 4; ++r)
                    pb[((size_t)(sp * 512 + row + r)) * 3072 + col] = acc[mc][fi][fj][r];
            }
        }
}

// ---------------------------------------------------------------------------
// K8: reduce 4 split-K partials + bias/gain -> out [512,3000]
// ---------------------------------------------------------------------------
__global__ __launch_bounds__(256) void k_red(const float* __restrict__ pb,
                                             const float* __restrict__ lin_b,
                                             const float* __restrict__ out_gain,
                                             const float* __restrict__ out_bias,
                                             float* __restrict__ out) {
    int col = blockIdx.x * 256 + threadIdx.x;
    if (col >= D_OUT) return;
    int row = blockIdx.y;
    size_t base = (size_t)row * 3072 + col;
    const size_t stride = (size_t)512 * 3072;
    float s = pb[base] + pb[base + stride] + pb[base + 2 * stride] + pb[base + 3 * stride];
    float g = out_gain[0];
    out[(size_t)row * D_OUT + col] = s * g + lin_b[col] * g + out_bias[0];
}

// ---------------------------------------------------------------------------
// Workspace layout (bytes)
// ---------------------------------------------------------------------------
#define SZ_ROWF ((size_t)B_ * D_TRF * 4)           // 10,485,760
#define SZ_ROWB ((size_t)B_ * D_TRF * 2)           // 5,242,880
#define OFF_CL  ((size_t)0)
#define OFF_H   (OFF_CL + SZ_ROWF)
#define OFF_XN  (OFF_H + SZ_ROWF)                  // xn bf16; reused as x2b
#define OFF_QB  (OFF_XN + SZ_ROWB)
#define OFF_KB  (OFF_QB + SZ_ROWB)
#define OFF_VB  (OFF_KB + SZ_ROWB)
#define OFF_YB  (OFF_VB + SZ_ROWB)
#define OFF_WSM (OFF_YB + SZ_ROWB)                 // 4 x 51200 B
#define OFF_WB  (OFF_WSM + (size_t)4 * E_ * E_ * 2)
// end = OFF_WB + 3072*5120*2 = 78,848,000 bytes
// pb (head-GEMM partials, 4*512*3072*4 = 25,165,824 B) aliases OFF_CL..:
// cl/h/xn are all dead once k_bt3 has run, and 25.2 MB < OFF_QB (26.2 MB).

extern "C" void kernel_launch(void* const* d_in, const int* in_sizes, int n_in,
                              void* d_out, int out_size, void* d_ws, size_t ws_size,
                              hipStream_t stream) {
    const float* x        = (const float*)d_in[0];
    const float* stdv     = (const float*)d_in[1];
    const float* meanv    = (const float*)d_in[2];
    const float* mat      = (const float*)d_in[3];
    const float* ln_g     = (const float*)d_in[4];
    const float* ln_b     = (const float*)d_in[5];
    const float* wq       = (const float*)d_in[6];
    const float* bq       = (const float*)d_in[7];
    const float* wk       = (const float*)d_in[8];
    const float* bk       = (const float*)d_in[9];
    const float* wv       = (const float*)d_in[10];
    const float* bv       = (const float*)d_in[11];
    const float* bt_w     = (const float*)d_in[12];
    const float* bt_b     = (const float*)d_in[13];
    const float* bt_gain  = (const float*)d_in[14];
    const float* bt_bias  = (const float*)d_in[15];
    const float* sup_g    = (const float*)d_in[16];
    const float* sup_b    = (const float*)d_in[17];
    const float* lin_w    = (const float*)d_in[18];
    const float* lin_b    = (const float*)d_in[19];
    const float* out_gain = (const float*)d_in[20];
    const float* out_bias = (const float*)d_in[21];

    char* ws = (char*)d_ws;
    float* cl = (float*)(ws + OFF_CL);
    float* h  = (float*)(ws + OFF_H);
    unsigned short* xn  = (unsigned short*)(ws + OFF_XN);
    unsigned short* x2b = xn;   // xn dead after k_qkv3
    unsigned short* Qb  = (unsigned short*)(ws + OFF_QB);
    unsigned short* Kb  = (unsigned short*)(ws + OFF_KB);
    unsigned short* Vb  = (unsigned short*)(ws + OFF_VB);
    unsigned short* yb  = (unsigned short*)(ws + OFF_YB);
    unsigned short* wqb = (unsigned short*)(ws + OFF_WSM);
    unsigned short* wkb = wqb + E_ * E_;
    unsigned short* wvb = wkb + E_ * E_;
    unsigned short* wtb = wvb + E_ * E_;
    unsigned short* wb  = (unsigned short*)(ws + OFF_WB);
    float* pb = (float*)(ws + OFF_CL);   // aliases cl/h/xn (dead by k_lin6)
    float* out = (float*)d_out;

    k_castw<<<15360, 256, 0, stream>>>(lin_w, wb);
    k_cast_small<<<100, 256, 0, stream>>>(wq, wk, wv, bt_w, wqb, wkb, wvb, wtb);
    k_cl<<<dim3(64, 4), 256, 0, stream>>>(x, stdv, meanv, mat, cl);
    k_ln<<<512, 256, 0, stream>>>(cl, ln_g, ln_b, xn);
    k_qkv3<<<dim3(256, 6), 256, 0, stream>>>(xn, wqb, wkb, wvb, bq, bk, bv, Qb, Kb, Vb);
    k_attn3<<<512, 256, 0, stream>>>(Qb, Kb, Vb, cl, bt_gain, bt_bias, h, x2b);
    k_bt3<<<dim3(256, 2), 256, 0, stream>>>(x2b, wtb, bt_b, sup_g, sup_b, h, yb);
    k_lin6<<<256, 256, 0, stream>>>(yb, wb, pb);
    k_red<<<dim3(12, 512), 256, 0, stream>>>(pb, lin_b, out_gain, out_bias, out);
}

// Round 11
// 291.610 us; speedup vs baseline: 1.2086x; 1.0124x over previous
//
#include <hip/hip_runtime.h>

// Problem constants
#define B_    512
#define D_TRF 5120
#define P_    32
#define E_    160
#define D_OUT 3000
#define PAD_  61
#define D_CL  4998
#define INV_SCALE 0.07905694150420949f   // 1/sqrt(160)
#define N_PAD 3072          // lin_w rows padded (64 tiles of 48)

typedef __attribute__((ext_vector_type(4))) float floatx4;
typedef __attribute__((ext_vector_type(16))) float floatx16;
typedef __attribute__((ext_vector_type(8))) short short8;

static __device__ __forceinline__ unsigned short f2bf(float f) {
    unsigned int u = __float_as_uint(f);
    unsigned int r = (u + 0x7fffu + ((u >> 16) & 1u)) >> 16;
    return (unsigned short)r;
}
static __device__ __forceinline__ float bf2f(unsigned short u) {
    return __uint_as_float(((unsigned int)u) << 16);
}
static __device__ __forceinline__ void load_lds16(const void* g, void* lds) {
    __builtin_amdgcn_global_load_lds(
        (const __attribute__((address_space(1))) unsigned int*)g,
        (__attribute__((address_space(3))) unsigned int*)lds, 16, 0, 0);
}

// ---------------------------------------------------------------------------
// K0: cast lin_w [3000,5120] f32 -> [3072,5120] bf16 (pad rows zeroed)
// ---------------------------------------------------------------------------
__global__ __launch_bounds__(256) void k_castw(const float* __restrict__ w,
                                               unsigned short* __restrict__ wb) {
    size_t i4 = ((size_t)blockIdx.x * 256 + threadIdx.x) * 4;
    size_t o = i4 / D_TRF;
    ushort4 s;
    if (o < D_OUT) {
        float4 v = *(const float4*)(w + i4);
        s.x = f2bf(v.x); s.y = f2bf(v.y); s.z = f2bf(v.z); s.w = f2bf(v.w);
    } else {
        s.x = s.y = s.z = s.w = 0;
    }
    *(ushort4*)(wb + i4) = s;
}

// ---------------------------------------------------------------------------
// K0b: cast wq/wk/wv ([f][e], already B-operand layout) to bf16;
//      transpose bt_w -> wtb[f][e] = bt_w[e][f].
// ---------------------------------------------------------------------------
__global__ __launch_bounds__(256) void k_cast_small(const float* __restrict__ wq,
                                                    const float* __restrict__ wk,
                                                    const float* __restrict__ wv,
                                                    const float* __restrict__ btw,
                                                    unsigned short* __restrict__ wqb,
                                                    unsigned short* __restrict__ wkb,
                                                    unsigned short* __restrict__ wvb,
                                                    unsigned short* __restrict__ wtb) {
    int idx = blockIdx.x * 256 + threadIdx.x;   // < 25600
    wqb[idx] = f2bf(wq[idx]);
    wkb[idx] = f2bf(wk[idx]);
    wvb[idx] = f2bf(wv[idx]);
    int f = idx / E_, e = idx - f * E_;
    wtb[idx] = f2bf(btw[(size_t)e * E_ + f]);
}

// ---------------------------------------------------------------------------
// K1: cl = (x*std+mean) @ mat, with 61-zero pad both sides -> [512,5120]
// ---------------------------------------------------------------------------
__global__ __launch_bounds__(256) void k_cl(const float* __restrict__ x,
                                            const float* __restrict__ stdv,
                                            const float* __restrict__ meanv,
                                            const float* __restrict__ mat,
                                            float* __restrict__ cl) {
    int bg = blockIdx.x, jc = blockIdx.y, tid = threadIdx.x;
    __shared__ float t[8 * 64];
    for (int idx = tid; idx < 8 * 64; idx += 256) {
        int i = idx >> 6, k = idx & 63;
        t[idx] = x[(size_t)(bg * 8 + i) * 64 + k] * stdv[k] + meanv[k];
    }
    __syncthreads();

    if (jc == 0) {
        for (int idx = tid; idx < 8 * PAD_; idx += 256) {
            int i = idx / PAD_, jj = idx - i * PAD_;
            cl[(size_t)(bg * 8 + i) * D_TRF + jj] = 0.f;
        }
    } else if (jc == 3) {
        for (int idx = tid; idx < 8 * PAD_; idx += 256) {
            int i = idx / PAD_, jj = idx - i * PAD_;
            cl[(size_t)(bg * 8 + i) * D_TRF + (D_TRF - PAD_) + jj] = 0.f;
        }
    }

    int j0 = jc * 1250;
    int jend = min(D_CL, j0 + 1250);
    for (int j = j0 + tid; j < jend; j += 256) {
        float acc[8] = {};
        #pragma unroll 16
        for (int k = 0; k < 64; ++k) {
            float m = mat[(size_t)k * D_CL + j];
            #pragma unroll
            for (int i = 0; i < 8; ++i) acc[i] += t[i * 64 + k] * m;
        }
        #pragma unroll
        for (int i = 0; i < 8; ++i)
            cl[(size_t)(bg * 8 + i) * D_TRF + PAD_ + j] = acc[i];
    }
}

// ---------------------------------------------------------------------------
// K2: LayerNorm cl row -> xn bf16 [16384,160]. grid = 512 (one b each)
// ---------------------------------------------------------------------------
__global__ __launch_bounds__(256) void k_ln(const float* __restrict__ cl,
                                            const float* __restrict__ ln_g,
                                            const float* __restrict__ ln_b,
                                            unsigned short* __restrict__ xn) {
    int b = blockIdx.x, tid = threadIdx.x;
    __shared__ float redA[4], redB[4];
    __shared__ float sMu, sRstd;
    const float* row = cl + (size_t)b * D_TRF;

    float s = 0.f, s2 = 0.f;
    #pragma unroll
    for (int it = 0; it < 5; ++it) {
        int i4 = (it * 256 + tid) * 4;
        float4 v = *(const float4*)(row + i4);
        s += v.x + v.y + v.z + v.w;
        s2 += v.x * v.x + v.y * v.y + v.z * v.z + v.w * v.w;
    }
    #pragma unroll
    for (int off = 32; off; off >>= 1) {
        s  += __shfl_down(s, off);
        s2 += __shfl_down(s2, off);
    }
    if ((tid & 63) == 0) { redA[tid >> 6] = s; redB[tid >> 6] = s2; }
    __syncthreads();
    if (tid == 0) {
        float S = redA[0] + redA[1] + redA[2] + redA[3];
        float S2 = redB[0] + redB[1] + redB[2] + redB[3];
        float mu = S / (float)D_TRF;
        float var = S2 / (float)D_TRF - mu * mu;
        sMu = mu; sRstd = rsqrtf(var + 1e-5f);
    }
    __syncthreads();
    float mu = sMu, rs = sRstd;
    #pragma unroll
    for (int it = 0; it < 5; ++it) {
        int i4 = (it * 256 + tid) * 4;
        float4 v = *(const float4*)(row + i4);
        float4 g = *(const float4*)(ln_g + i4);
        float4 be = *(const float4*)(ln_b + i4);
        ushort4 o;
        o.x = f2bf((v.x - mu) * rs * g.x + be.x);
        o.y = f2bf((v.y - mu) * rs * g.y + be.y);
        o.z = f2bf((v.z - mu) * rs * g.z + be.z);
        o.w = f2bf((v.w - mu) * rs * g.w + be.w);
        *(ushort4*)(xn + (size_t)b * D_TRF + i4) = o;
    }
}

// ---------------------------------------------------------------------------
// K3: QKV via MFMA, register-resident B-frags loaded straight from global.
// V is stored TRANSPOSED per b: Vt[b*5120 + e*32 + q] (q contiguous) so the
// attention PV B-frags become single 16B vector loads.
// ---------------------------------------------------------------------------
__global__ __launch_bounds__(256) void k_qkv3(const unsigned short* __restrict__ xn,
                                              const unsigned short* __restrict__ wqb,
                                              const unsigned short* __restrict__ wkb,
                                              const unsigned short* __restrict__ wvb,
                                              const float* __restrict__ bq,
                                              const float* __restrict__ bk,
                                              const float* __restrict__ bv,
                                              unsigned short* __restrict__ Qb,
                                              unsigned short* __restrict__ Kb,
                                              unsigned short* __restrict__ Vt) {
    int tid = threadIdx.x, wid = tid >> 6, lane = tid & 63;
    int l16 = lane & 15, quad = lane >> 4;
    int m0 = blockIdx.x * 64 + wid * 16;
    int sel = blockIdx.y;                 // 0..5
    int mat = sel >> 1;
    int cf0 = (sel & 1) * 5;

    const unsigned short* wsrc = (mat == 0) ? wqb : (mat == 1) ? wkb : wvb;
    const float* bias          = (mat == 0) ? bq  : (mat == 1) ? bk  : bv;
    unsigned short* outp       = (mat == 0) ? Qb  : Kb;

    short8 a[5];
    const unsigned short* arow = xn + (size_t)(m0 + l16) * E_ + quad * 8;
    #pragma unroll
    for (int kc = 0; kc < 5; ++kc) a[kc] = *(const short8*)(arow + kc * 32);

    #pragma unroll
    for (int c = 0; c < 5; ++c) {
        int cf = cf0 + c;
        floatx4 acc = {0.f, 0.f, 0.f, 0.f};
        const unsigned short* bp = wsrc + (size_t)(cf * 16 + l16) * E_ + quad * 8;
        #pragma unroll
        for (int kc = 0; kc < 5; ++kc) {
            short8 bf = *(const short8*)(bp + kc * 32);
            acc = __builtin_amdgcn_mfma_f32_16x16x32_bf16(a[kc], bf, acc, 0, 0, 0);
        }
        int col = cf * 16 + l16;
        float bb = bias[col];
        if (mat == 2) {
            // transposed store: Vt[b][e=col][q=p]
            #pragma unroll
            for (int r = 0; r < 4; ++r) {
                int row = m0 + quad * 4 + r;
                int b_ = row >> 5, p = row & 31;
                Vt[(size_t)b_ * D_TRF + col * 32 + p] = f2bf(acc[r] + bb);
            }
        } else {
            size_t o = (size_t)(m0 + quad * 4) * E_ + col;
            #pragma unroll
            for (int r = 0; r < 4; ++r)
                outp[o + (size_t)r * E_] = f2bf(acc[r] + bb);
        }
    }
}

// ---------------------------------------------------------------------------
// K4: MFMA attention v4, 4 waves per b (grid 512 x 256). All waves compute
// S = QK^T redundantly; softmax over p in-reg; wave 0 writes att->LDS;
// waves split the 5 PV e-chunks. PV B-frags = vector loads from Vt
// (B[n=e][k=q] = Vt[e*32+q], q-contiguous) — replaces 8 scalar loads each.
// ---------------------------------------------------------------------------
__global__ __launch_bounds__(256) void k_attn4(const unsigned short* __restrict__ Q,
                                               const unsigned short* __restrict__ K,
                                               const unsigned short* __restrict__ Vt,
                                               const float* __restrict__ cl,
                                               const float* __restrict__ bt_gain,
                                               const float* __restrict__ bt_bias,
                                               float* __restrict__ h,
                                               unsigned short* __restrict__ x2b) {
    int b = blockIdx.x;
    int tid = threadIdx.x, wid = tid >> 6, lane = tid & 63;
    int l32 = lane & 31, hi = lane >> 5;
    __shared__ __align__(16) unsigned short Satt[32 * 40];   // row stride 40 bf16

    const unsigned short* Qg = Q + (size_t)b * D_TRF;
    const unsigned short* Kg = K + (size_t)b * D_TRF;
    const unsigned short* Vg = Vt + (size_t)b * D_TRF;

    // ---- S = Q K^T (redundant per wave) ----
    floatx16 S = {0.f, 0.f, 0.f, 0.f, 0.f, 0.f, 0.f, 0.f,
                  0.f, 0.f, 0.f, 0.f, 0.f, 0.f, 0.f, 0.f};
    #pragma unroll
    for (int kc = 0; kc < 10; ++kc) {
        int e0 = kc * 16;
        short8 aq = *(const short8*)(Qg + l32 * E_ + e0 + hi * 8);
        short8 bk = *(const short8*)(Kg + l32 * E_ + e0 + hi * 8);
        S = __builtin_amdgcn_mfma_f32_32x32x16_bf16(aq, bk, S, 0, 0, 0);
    }

    // ---- softmax over p (C-layout rows): in-lane 16 regs + shfl_xor(32) ----
    float mx = -1e30f;
    #pragma unroll
    for (int r = 0; r < 16; ++r) { S[r] *= INV_SCALE; mx = fmaxf(mx, S[r]); }
    mx = fmaxf(mx, __shfl_xor(mx, 32));
    float ex[16];
    float sum = 0.f;
    #pragma unroll
    for (int r = 0; r < 16; ++r) { ex[r] = expf(S[r] - mx); sum += ex[r]; }
    sum += __shfl_xor(sum, 32);
    float inv = 1.f / sum;

    // ---- att -> LDS [p][q] bf16 (wave 0 only) ----
    if (wid == 0) {
        #pragma unroll
        for (int r = 0; r < 16; ++r) {
            int p = (r & 3) + 8 * (r >> 2) + 4 * hi;
            Satt[p * 40 + l32] = f2bf(ex[r] * inv);
        }
    }
    __syncthreads();

    // ---- A-frags for PV ----
    short8 a0 = *(const short8*)(&Satt[l32 * 40 + hi * 8]);
    short8 a1 = *(const short8*)(&Satt[l32 * 40 + 16 + hi * 8]);

    const float* clr = cl + (size_t)b * D_TRF;
    float gg = bt_gain[0], bb2 = bt_bias[0];

    for (int t = wid; t < 5; t += 4) {
        int e0 = t * 32;
        short8 b0 = *(const short8*)(Vg + (e0 + l32) * 32 + hi * 8);
        short8 b1 = *(const short8*)(Vg + (e0 + l32) * 32 + 16 + hi * 8);
        floatx16 acc = {0.f, 0.f, 0.f, 0.f, 0.f, 0.f, 0.f, 0.f,
                        0.f, 0.f, 0.f, 0.f, 0.f, 0.f, 0.f, 0.f};
        acc = __builtin_amdgcn_mfma_f32_32x32x16_bf16(a0, b0, acc, 0, 0, 0);
        acc = __builtin_amdgcn_mfma_f32_32x32x16_bf16(a1, b1, acc, 0, 0, 0);
        #pragma unroll
        for (int r = 0; r < 16; ++r) {
            int p = (r & 3) + 8 * (r >> 2) + 4 * hi;
            int idx = p * E_ + e0 + l32;
            float hv = acc[r] + clr[idx];
            h[(size_t)b * D_TRF + idx] = hv;
            x2b[(size_t)b * D_TRF + idx] = f2bf(hv * gg + bb2);
        }
    }
}

// ---------------------------------------------------------------------------
// K5: Better_Transformer via MFMA, register B-frags from global (no LDS).
// ---------------------------------------------------------------------------
__global__ __launch_bounds__(256) void k_bt3(const unsigned short* __restrict__ x2b,
                                             const unsigned short* __restrict__ wtb,
                                             const float* __restrict__ bt_b,
                                             const float* __restrict__ sup_g,
                                             const float* __restrict__ sup_b,
                                             const float* __restrict__ h,
                                             unsigned short* __restrict__ yb) {
    int tid = threadIdx.x, wid = tid >> 6, lane = tid & 63;
    int l16 = lane & 15, quad = lane >> 4;
    int m0 = blockIdx.x * 64 + wid * 16;
    int cf0 = blockIdx.y * 5;

    short8 a[5];
    const unsigned short* arow = x2b + (size_t)(m0 + l16) * E_ + quad * 8;
    #pragma unroll
    for (int kc = 0; kc < 5; ++kc) a[kc] = *(const short8*)(arow + kc * 32);

    #pragma unroll
    for (int c = 0; c < 5; ++c) {
        int cf = cf0 + c;
        floatx4 acc = {0.f, 0.f, 0.f, 0.f};
        const unsigned short* bp = wtb + (size_t)(cf * 16 + l16) * E_ + quad * 8;
        #pragma unroll
        for (int kc = 0; kc < 5; ++kc) {
            short8 bf = *(const short8*)(bp + kc * 32);
            acc = __builtin_amdgcn_mfma_f32_16x16x32_bf16(a[kc], bf, acc, 0, 0, 0);
        }
        int col = cf * 16 + l16;
        float bb = bt_b[col];
        #pragma unroll
        for (int r = 0; r < 4; ++r) {
            int row = m0 + quad * 4 + r;
            int p = row & 31;
            int i = p * E_ + col;
            float o = acc[r] + bb;
            float sig = 1.f / (1.f + expf(-sup_b[i] * o));
            float y = (sup_g[i] + sig * (1.f - sup_g[i])) * o + h[(size_t)row * E_ + col];
            yb[(size_t)row * E_ + col] = f2bf(y);
        }
    }
}

// ---------------------------------------------------------------------------
// K7: head GEMM v7 — k_lin6's bulk-staged structure at 8 waves/block.
// 512 threads; each wave owns 64 of the 512 m-rows (no mc loop, acc[4][3]
// ~120 VGPR -> 2 waves/SIMD co-scheduled: staging drains and A-load latency
// now hide under the other wave's MFMA stream, which 4-wave variants could
// not do — that was the shared ~57 us wall of k_lin2/4/6).
// grid 256 = 64 n-tiles(48) x 4 k-splits(1280); B bulk-staged per 640-half
// via global_load_lds with global-side XOR chunk swizzle; A direct from L2
// with register ping-pong; partials -> pb, reduced by k_red. No atomics.
// ---------------------------------------------------------------------------
__global__ __launch_bounds__(512) void k_lin7(const unsigned short* __restrict__ yb,
                                              const unsigned short* __restrict__ wb,
                                              float* __restrict__ pb) {
    __shared__ __align__(16) unsigned short Bs[48 * 640];   // 60 KB
    int blk = blockIdx.x;
    int nt = blk & 63, sp = blk >> 6;        // 64 n-tiles, 4 k-splits
    int tid = threadIdx.x, wid = tid >> 6, lane = tid & 63;
    int l16 = lane & 15, quad = lane >> 4;
    int br7 = l16 & 7;

    floatx4 acc[4][3];
    #pragma unroll
    for (int i = 0; i < 4; ++i)
        #pragma unroll
        for (int j = 0; j < 3; ++j) acc[i][j] = (floatx4){0.f, 0.f, 0.f, 0.f};

    int bbase[3];
    #pragma unroll
    for (int fj = 0; fj < 3; ++fj) bbase[fj] = (fj * 16 + l16) * 640;

    const int k0 = sp * 1280;
    for (int h = 0; h < 2; ++h) {
        int kh = k0 + h * 640;
        if (h) __syncthreads();              // all waves done reading half 0
        #pragma unroll
        for (int i = 0; i < 8; ++i) {        // 3840 slots of 16 B, 512 thr
            int u = i * 512 + tid;
            if (u < 3840) {                  // boundary at wave edge (3840=7.5*512)
                int row = u / 80;            // 80 chunks per row
                int c = u - row * 80;
                int g = c ^ (row & 7);       // XOR swizzle on global side
                load_lds16(wb + (size_t)(nt * 48 + row) * D_TRF + kh + g * 8,
                           (char*)Bs + (size_t)u * 16);
            }
        }
        __syncthreads();

        const unsigned short* Ar[4];
        #pragma unroll
        for (int fi = 0; fi < 4; ++fi)
            Ar[fi] = yb + (size_t)(wid * 64 + fi * 16 + l16) * D_TRF + quad * 8 + kh;

        short8 aP[4], bP[3], aN[4], bN[3];
        #pragma unroll
        for (int fi = 0; fi < 4; ++fi) aP[fi] = *(const short8*)(Ar[fi]);
        #pragma unroll
        for (int fj = 0; fj < 3; ++fj)
            bP[fj] = *(const short8*)(Bs + bbase[fj] + ((quad ^ br7) * 8));

        for (int it = 0; it < 10; ++it) {
            int s1 = 2 * it + 1;
            #pragma unroll
            for (int fi = 0; fi < 4; ++fi)
                aN[fi] = *(const short8*)(Ar[fi] + s1 * 32);
            #pragma unroll
            for (int fj = 0; fj < 3; ++fj) {
                int c = s1 * 4 + quad;
                bN[fj] = *(const short8*)(Bs + bbase[fj] + ((c ^ br7) * 8));
            }
            #pragma unroll
            for (int fi = 0; fi < 4; ++fi)
                #pragma unroll
                for (int fj = 0; fj < 3; ++fj)
                    acc[fi][fj] = __builtin_amdgcn_mfma_f32_16x16x32_bf16(
                        aP[fi], bP[fj], acc[fi][fj], 0, 0, 0);

            int s2 = (it < 9) ? 2 * it + 2 : 0;   // wrap: dummy, unused
            #pragma unroll
            for (int fi = 0; fi < 4; ++fi)
                aP[fi] = *(const short8*)(Ar[fi] + s2 * 32);
            #pragma unroll
            for (int fj = 0; fj < 3; ++fj) {
                int c = s2 * 4 + quad;
                bP[fj] = *(const short8*)(Bs + bbase[fj] + ((c ^ br7) * 8));
            }
            #pragma unroll
            for (int fi = 0; fi < 4; ++fi)
                #pragma unroll
                for (int fj = 0; fj < 3; ++fj)
                    acc[fi][fj] = __builtin_amdgcn_mfma_f32_16x16x32_bf16(
                        aN[fi], bN[fj], acc[fi][fj], 0, 0, 0);
        }
    }

    // epilogue: plain coalesced stores of partials
    #pragma unroll
    for (int fi = 0; fi < 4; ++fi) {
        int row = wid * 64 + fi * 16 + quad * 4;
        #pragma unroll
        for (int fj = 0; fj < 3; ++fj) {
            int col = nt * 48 + fj * 16 + l16;
            #pragma unroll
            for (int r = 0; r < 4; ++r)
                pb[((size_t)(sp * 512 + row + r)) * 3072 + col] = acc[fi][fj][r];
        }
    }
}

// ---------------------------------------------------------------------------
// K8: reduce 4 split-K partials + bias/gain -> out [512,3000]
// ---------------------------------------------------------------------------
__global__ __launch_bounds__(256) void k_red(const float* __restrict__ pb,
                                             const float* __restrict__ lin_b,
                                             const float* __restrict__ out_gain,
                                             const float* __restrict__ out_bias,
                                             float* __restrict__ out) {
    int col = blockIdx.x * 256 + threadIdx.x;
    if (col >= D_OUT) return;
    int row = blockIdx.y;
    size_t base = (size_t)row * 3072 + col;
    const size_t stride = (size_t)512 * 3072;
    float s = pb[base] + pb[base + stride] + pb[base + 2 * stride] + pb[base + 3 * stride];
    float g = out_gain[0];
    out[(size_t)row * D_OUT + col] = s * g + lin_b[col] * g + out_bias[0];
}

// ---------------------------------------------------------------------------
// Workspace layout (bytes)
// ---------------------------------------------------------------------------
#define SZ_ROWF ((size_t)B_ * D_TRF * 4)           // 10,485,760
#define SZ_ROWB ((size_t)B_ * D_TRF * 2)           // 5,242,880
#define OFF_CL  ((size_t)0)
#define OFF_H   (OFF_CL + SZ_ROWF)
#define OFF_XN  (OFF_H + SZ_ROWF)                  // xn bf16; reused as x2b
#define OFF_QB  (OFF_XN + SZ_ROWB)
#define OFF_KB  (OFF_QB + SZ_ROWB)
#define OFF_VB  (OFF_KB + SZ_ROWB)                 // holds Vt [b][e][q]
#define OFF_YB  (OFF_VB + SZ_ROWB)
#define OFF_WSM (OFF_YB + SZ_ROWB)                 // 4 x 51200 B
#define OFF_WB  (OFF_WSM + (size_t)4 * E_ * E_ * 2)
// end = OFF_WB + 3072*5120*2 = 78,848,000 bytes
// pb (head-GEMM partials, 4*512*3072*4 = 25,165,824 B) aliases OFF_CL..:
// cl/h/xn are all dead once k_bt3 has run, and 25.2 MB < OFF_QB (26.2 MB).

extern "C" void kernel_launch(void* const* d_in, const int* in_sizes, int n_in,
                              void* d_out, int out_size, void* d_ws, size_t ws_size,
                              hipStream_t stream) {
    const float* x        = (const float*)d_in[0];
    const float* stdv     = (const float*)d_in[1];
    const float* meanv    = (const float*)d_in[2];
    const float* mat      = (const float*)d_in[3];
    const float* ln_g     = (const float*)d_in[4];
    const float* ln_b     = (const float*)d_in[5];
    const float* wq       = (const float*)d_in[6];
    const float* bq       = (const float*)d_in[7];
    const float* wk       = (const float*)d_in[8];
    const float* bk       = (const float*)d_in[9];
    const float* wv       = (const float*)d_in[10];
    const float* bv       = (const float*)d_in[11];
    const float* bt_w     = (const float*)d_in[12];
    const float* bt_b     = (const float*)d_in[13];
    const float* bt_gain  = (const float*)d_in[14];
    const float* bt_bias  = (const float*)d_in[15];
    const float* sup_g    = (const float*)d_in[16];
    const float* sup_b    = (const float*)d_in[17];
    const float* lin_w    = (const float*)d_in[18];
    const float* lin_b    = (const float*)d_in[19];
    const float* out_gain = (const float*)d_in[20];
    const float* out_bias = (const float*)d_in[21];

    char* ws = (char*)d_ws;
    float* cl = (float*)(ws + OFF_CL);
    float* h  = (float*)(ws + OFF_H);
    unsigned short* xn  = (unsigned short*)(ws + OFF_XN);
    unsigned short* x2b = xn;   // xn dead after k_qkv3
    unsigned short* Qb  = (unsigned short*)(ws + OFF_QB);
    unsigned short* Kb  = (unsigned short*)(ws + OFF_KB);
    unsigned short* Vt  = (unsigned short*)(ws + OFF_VB);
    unsigned short* yb  = (unsigned short*)(ws + OFF_YB);
    unsigned short* wqb = (unsigned short*)(ws + OFF_WSM);
    unsigned short* wkb = wqb + E_ * E_;
    unsigned short* wvb = wkb + E_ * E_;
    unsigned short* wtb = wvb + E_ * E_;
    unsigned short* wb  = (unsigned short*)(ws + OFF_WB);
    float* pb = (float*)(ws + OFF_CL);   // aliases cl/h/xn (dead by k_lin7)
    float* out = (float*)d_out;

    k_castw<<<15360, 256, 0, stream>>>(lin_w, wb);
    k_cast_small<<<100, 256, 0, stream>>>(wq, wk, wv, bt_w, wqb, wkb, wvb, wtb);
    k_cl<<<dim3(64, 4), 256, 0, stream>>>(x, stdv, meanv, mat, cl);
    k_ln<<<512, 256, 0, stream>>>(cl, ln_g, ln_b, xn);
    k_qkv3<<<dim3(256, 6), 256, 0, stream>>>(xn, wqb, wkb, wvb, bq, bk, bv, Qb, Kb, Vt);
    k_attn4<<<512, 256, 0, stream>>>(Qb, Kb, Vt, cl, bt_gain, bt_bias, h, x2b);
    k_bt3<<<dim3(256, 2), 256, 0, stream>>>(x2b, wtb, bt_b, sup_g, sup_b, h, yb);
    k_lin7<<<256, 512, 0, stream>>>(yb, wb, pb);
    k_red<<<dim3(12, 512), 256, 0, stream>>>(pb, lin_b, out_gain, out_bias, out);
}